// Round 21
// baseline (140.169 us; speedup 1.0000x reference)
//
#include <hip/hip_runtime.h>
#include <math.h>
#include <float.h>

#define N_NODES 50000
#define N_EDGES 800000
#define IN_DIM  512
#define HID_DIM 64
#define OUT_DIM 40
#define GEMM1_BLOCKS 782
#define FILL_BLOCKS 1568        // 8 groups x 196 blocks
#define NODES_PER_GRP 6250      // 50000 / 8
#define BCAP 96                 // bucket capacity (deg ~ Poisson(16))
#define AGG_Q 1563              // ceil(6250/4)
#define AGG_BLOCKS (8 * AGG_Q)  // 12504

typedef __attribute__((ext_vector_type(8))) short bf16x8;
typedef __attribute__((ext_vector_type(4))) float f32x4;

#define GLOAD_LDS(SRC, DST)                                                   \
  __builtin_amdgcn_global_load_lds(                                           \
      (const __attribute__((address_space(1))) void*)(SRC),                   \
      (__attribute__((address_space(3))) void*)(DST), 16, 0, 0)

// ---------------- Threefry-2x32, JAX-exact, key = (0, 42) ----------------
__device__ __forceinline__ unsigned rotl32(unsigned v, int n) {
  return (v << n) | (v >> (32 - n));
}

__device__ __forceinline__ void threefry2x32_0_42(unsigned x0, unsigned x1,
                                                  unsigned &o0, unsigned &o1) {
  const unsigned ks0 = 0u;
  const unsigned ks1 = 42u;
  const unsigned ks2 = 0u ^ 42u ^ 0x1BD11BDAu;
  x0 += ks0; x1 += ks1;
  x0 += x1; x1 = rotl32(x1, 13); x1 ^= x0;
  x0 += x1; x1 = rotl32(x1, 15); x1 ^= x0;
  x0 += x1; x1 = rotl32(x1, 26); x1 ^= x0;
  x0 += x1; x1 = rotl32(x1,  6); x1 ^= x0;
  x0 += ks1; x1 += ks2 + 1u;
  x0 += x1; x1 = rotl32(x1, 17); x1 ^= x0;
  x0 += x1; x1 = rotl32(x1, 29); x1 ^= x0;
  x0 += x1; x1 = rotl32(x1, 16); x1 ^= x0;
  x0 += x1; x1 = rotl32(x1, 24); x1 ^= x0;
  x0 += ks2; x1 += ks0 + 2u;
  x0 += x1; x1 = rotl32(x1, 13); x1 ^= x0;
  x0 += x1; x1 = rotl32(x1, 15); x1 ^= x0;
  x0 += x1; x1 = rotl32(x1, 26); x1 ^= x0;
  x0 += x1; x1 = rotl32(x1,  6); x1 ^= x0;
  x0 += ks0; x1 += ks1 + 3u;
  x0 += x1; x1 = rotl32(x1, 17); x1 ^= x0;
  x0 += x1; x1 = rotl32(x1, 29); x1 ^= x0;
  x0 += x1; x1 = rotl32(x1, 16); x1 ^= x0;
  x0 += x1; x1 = rotl32(x1, 24); x1 ^= x0;
  x0 += ks1; x1 += ks2 + 4u;
  x0 += x1; x1 = rotl32(x1, 13); x1 ^= x0;
  x0 += x1; x1 = rotl32(x1, 15); x1 ^= x0;
  x0 += x1; x1 = rotl32(x1, 26); x1 ^= x0;
  x0 += x1; x1 = rotl32(x1,  6); x1 ^= x0;
  x0 += ks2; x1 += ks0 + 5u;
  o0 = x0; o1 = x1;
}

__device__ __forceinline__ unsigned short f2bf(float f) {
  unsigned u = __float_as_uint(f);
  unsigned r = u + 0x7FFFu + ((u >> 16) & 1u);   // RNE
  return (unsigned short)(r >> 16);
}

// ---------------- init: zero cnt + weight repack (fused, no deps) -----------
__global__ void k_init(const float* __restrict__ W1, const float* __restrict__ W2,
                       unsigned short* __restrict__ Wb1, float* __restrict__ w2t,
                       int* __restrict__ cnt) {
  int i = blockIdx.x * 256 + threadIdx.x;
  if (i < N_NODES) cnt[i] = 0;
  if (i < IN_DIM * HID_DIM) {
    int j = i & 7;
    int lane = (i >> 3) & 63;
    int cg = (i >> 9) & 3;
    int kb = i >> 11;
    int k = kb * 32 + ((lane >> 4) << 3) + j;
    int c = cg * 16 + (lane & 15);
    Wb1[i] = f2bf(W1[k * HID_DIM + c]);
  }
  if (i < HID_DIM * OUT_DIM) {
    int j = i >> 6;           // output col 0..39
    int k = i & 63;           // hidden idx
    w2t[i] = W2[k * OUT_DIM + j];
  }
}

// ---------------- bucket fill, standalone (no LDS -> full occupancy) --------
// Group = blockIdx&7 (XCD under round-robin) handles dst in its range; dst
// batch-preloaded (8 in flight); value partition -> correct under any mapping.
__global__ __launch_bounds__(512) void k_fill(const int* __restrict__ ei,
                                              int* __restrict__ cnt,
                                              unsigned short* __restrict__ elist2) {
  const int grp = blockIdx.x & 7;              // intended XCD
  const int ord = blockIdx.x >> 3;             // 0..195 within group
  const int lo = grp * NODES_PER_GRP;
  const int hi = lo + NODES_PER_GRP;
  const int ebase = ord * 512 + threadIdx.x;
  int dv[8];
#pragma unroll
  for (int i = 0; i < 8; ++i) {
    int e = ebase + i * (196 * 512);
    dv[i] = (e < N_EDGES) ? ei[N_EDGES + e] : -1;
  }
#pragma unroll
  for (int i = 0; i < 8; ++i) {
    if (dv[i] >= lo && dv[i] < hi) {
      int s = ei[ebase + i * (196 * 512)];
      int slot = atomicAdd(&cnt[dv[i]], 1);
      if (slot < BCAP) elist2[dv[i] * BCAP + slot] = (unsigned short)s;
    }
  }
}

// ---- gemm1 (MFMA bf16, async global_load_lds f32 staging, swizzled) --------
// 512 thr, 64 rows/block, K-chunk 64, dbuf 2x16KB LDS.
// LDS physical = linear ^ ((row&7)<<4); DMA source pre-swizzled identically;
// ds_read applies the same involution (rule #21).
__global__ __launch_bounds__(512) void k_gemm1(
    const float* __restrict__ x, const unsigned short* __restrict__ Wb1,
    unsigned short* __restrict__ ht1b) {
  __shared__ unsigned char sxa[2][16384];   // 64 rows x 64 f32 per chunk

  const int tid = threadIdx.x;
  const int lane = tid & 63;
  const int wave = tid >> 6;          // 0..7
  const int brow = blockIdx.x * 64;

  f32x4 acc[2];
  acc[0] = (f32x4){0.f, 0.f, 0.f, 0.f};
  acc[1] = (f32x4){0.f, 0.f, 0.f, 0.f};

  const bf16x8* __restrict__ Wv = (const bf16x8*)Wb1;

  int srow[2], soff[2];
#pragma unroll
  for (int i = 0; i < 2; ++i) {
    int p = wave * 2048 + i * 1024 + lane * 16;
    int row = p >> 8;
    int b = p & 255;
    int gr2 = brow + row;
    if (gr2 >= N_NODES) gr2 = N_NODES - 1;
    srow[i] = gr2;
    soff[i] = b ^ ((row & 7) << 4);   // byte offset within the 256B k-slice
  }

#define ISSUE(B, KC)                                                          \
  {                                                                           \
    _Pragma("unroll")                                                         \
    for (int i = 0; i < 2; ++i) {                                             \
      const char* src = (const char*)(x + (size_t)srow[i] * IN_DIM +          \
                                      (KC) * 64) + soff[i];                   \
      GLOAD_LDS(src, &sxa[B][wave * 2048 + i * 1024]);                        \
    }                                                                         \
  }

  ISSUE(0, 0)
  __syncthreads();

  const int arow = 16 * (wave & 3) + (lane & 15);   // logical row
  const int rsw = (arow & 7) << 4;
  const int kbyte = (lane >> 4) << 5;               // (lane>>4)*8 f32 = 32B
  const int cgb = 2 * (wave >> 2);                  // col-group base

  int buf = 0;
  for (int kc = 0; kc < 8; ++kc) {
    if (kc < 7) ISSUE(buf ^ 1, kc + 1)    // async DMA overlaps compute
#pragma unroll
    for (int ks = 0; ks < 2; ++ks) {
      int lin = arow * 256 + ks * 128 + kbyte;
      float4 fa = *(const float4*)(&sxa[buf][lin ^ rsw]);
      float4 fb = *(const float4*)(&sxa[buf][(lin + 16) ^ rsw]);
      union { unsigned short u[8]; bf16x8 v; } pk;
      pk.u[0] = f2bf(fa.x); pk.u[1] = f2bf(fa.y);
      pk.u[2] = f2bf(fa.z); pk.u[3] = f2bf(fa.w);
      pk.u[4] = f2bf(fb.x); pk.u[5] = f2bf(fb.y);
      pk.u[6] = f2bf(fb.z); pk.u[7] = f2bf(fb.w);
      int kb = kc * 2 + ks;
#pragma unroll
      for (int c = 0; c < 2; ++c) {
        bf16x8 b = Wv[(kb * 4 + cgb + c) * 64 + lane];
        acc[c] = __builtin_amdgcn_mfma_f32_16x16x32_bf16(pk.v, b, acc[c], 0, 0, 0);
      }
    }
    __syncthreads();                      // drains vmcnt -> next buf ready
    buf ^= 1;
  }
#undef ISSUE

#pragma unroll
  for (int q = 0; q < 4; ++q) {
    int grow = brow + 16 * (wave & 3) + ((lane >> 4) << 2) + q;
    if (grow < N_NODES) {
#pragma unroll
      for (int c = 0; c < 2; ++c) {
        ht1b[(size_t)grow * HID_DIM + (cgb + c) * 16 + (lane & 15)] =
            f2bf(acc[c][q]);
      }
    }
  }
}

// ---- agg1 + gemm2 fused (ushort buckets, XCD-aligned node mapping) ---------
__global__ __launch_bounds__(256) void k_agg1g2(const int* __restrict__ cnt,
                                                const unsigned short* __restrict__ elist2,
                                                const unsigned short* __restrict__ ht1b,
                                                const float* __restrict__ b1,
                                                const float* __restrict__ w2t,
                                                unsigned short* __restrict__ ht2b) {
  const int wave = threadIdx.x >> 6;
  const int lane = threadIdx.x & 63;
  const int dl = (blockIdx.x >> 3) * 4 + wave;
  if (dl >= NODES_PER_GRP) return;
  const int d = (blockIdx.x & 7) * NODES_PER_GRP + dl;
  const int g = lane >> 3;        // edge group 0..7
  const int fh = lane & 7;        // feature quad pair: quads fh and fh+8

  unsigned t0, t1;
  threefry2x32_0_42(0u, (unsigned)d * 64u + (unsigned)lane, t0, t1);
  unsigned long long keep = __ballot(!((t0 ^ t1) & 0x80000000u));

  int cn = cnt[d];
  if (cn > BCAP) cn = BCAP;
  const unsigned short* __restrict__ bucket = elist2 + d * BCAP;
  float4 a0 = {0.f, 0.f, 0.f, 0.f};
  float4 a1 = {0.f, 0.f, 0.f, 0.f};
#pragma unroll 2
  for (int j = g; j < cn; j += 8) {
    int s = bucket[j];
    float ds = rsqrtf((float)cnt[s] + 1.0f);
    const uint2* __restrict__ p = (const uint2*)(ht1b + (size_t)s * HID_DIM);
    uint2 q0 = p[fh];
    uint2 q1 = p[fh + 8];
    a0.x += __uint_as_float(q0.x << 16) * ds;
    a0.y += __uint_as_float(q0.x & 0xFFFF0000u) * ds;
    a0.z += __uint_as_float(q0.y << 16) * ds;
    a0.w += __uint_as_float(q0.y & 0xFFFF0000u) * ds;
    a1.x += __uint_as_float(q1.x << 16) * ds;
    a1.y += __uint_as_float(q1.x & 0xFFFF0000u) * ds;
    a1.z += __uint_as_float(q1.y << 16) * ds;
    a1.w += __uint_as_float(q1.y & 0xFFFF0000u) * ds;
  }
#pragma unroll
  for (int m = 32; m >= 8; m >>= 1) {
    a0.x += __shfl_xor(a0.x, m); a0.y += __shfl_xor(a0.y, m);
    a0.z += __shfl_xor(a0.z, m); a0.w += __shfl_xor(a0.w, m);
    a1.x += __shfl_xor(a1.x, m); a1.y += __shfl_xor(a1.y, m);
    a1.z += __shfl_xor(a1.z, m); a1.w += __shfl_xor(a1.w, m);
  }

  // self-loop (s = d), then bias + relu + dropout on ALL lanes
  float dd = rsqrtf((float)cn + 1.0f);
  {
    const uint2* __restrict__ ps = (const uint2*)(ht1b + (size_t)d * HID_DIM);
    uint2 s0 = ps[fh];
    uint2 s1 = ps[fh + 8];
    a0.x += __uint_as_float(s0.x << 16) * dd;
    a0.y += __uint_as_float(s0.x & 0xFFFF0000u) * dd;
    a0.z += __uint_as_float(s0.y << 16) * dd;
    a0.w += __uint_as_float(s0.y & 0xFFFF0000u) * dd;
    a1.x += __uint_as_float(s1.x << 16) * dd;
    a1.y += __uint_as_float(s1.x & 0xFFFF0000u) * dd;
    a1.z += __uint_as_float(s1.y << 16) * dd;
    a1.w += __uint_as_float(s1.y & 0xFFFF0000u) * dd;
  }
  float4 bb0 = *(const float4*)(b1 + fh * 4);
  float4 bb1 = *(const float4*)(b1 + fh * 4 + 32);
  int f0 = fh * 4;
  float4 v0, v1;
  v0.x = fmaxf(a0.x * dd + bb0.x, 0.f) * (((keep >> (f0 + 0)) & 1) ? 2.f : 0.f);
  v0.y = fmaxf(a0.y * dd + bb0.y, 0.f) * (((keep >> (f0 + 1)) & 1) ? 2.f : 0.f);
  v0.z = fmaxf(a0.z * dd + bb0.z, 0.f) * (((keep >> (f0 + 2)) & 1) ? 2.f : 0.f);
  v0.w = fmaxf(a0.w * dd + bb0.w, 0.f) * (((keep >> (f0 + 3)) & 1) ? 2.f : 0.f);
  v1.x = fmaxf(a1.x * dd + bb1.x, 0.f) * (((keep >> (f0 + 32)) & 1) ? 2.f : 0.f);
  v1.y = fmaxf(a1.y * dd + bb1.y, 0.f) * (((keep >> (f0 + 33)) & 1) ? 2.f : 0.f);
  v1.z = fmaxf(a1.z * dd + bb1.z, 0.f) * (((keep >> (f0 + 34)) & 1) ? 2.f : 0.f);
  v1.w = fmaxf(a1.w * dd + bb1.w, 0.f) * (((keep >> (f0 + 35)) & 1) ? 2.f : 0.f);

  // mini-GEMM: lane (g,fh) partials for cols j=g*5+c over its 8 k's;
  // reduce across fh via xor 1,2,4.
  const int jb = g * 5;
  float part[5];
#pragma unroll
  for (int c = 0; c < 5; ++c) {
    const float* __restrict__ wr = w2t + (jb + c) * 64;
    float4 wA = *(const float4*)(wr + f0);
    float4 wB = *(const float4*)(wr + 32 + f0);
    part[c] = v0.x * wA.x + v0.y * wA.y + v0.z * wA.z + v0.w * wA.w +
              v1.x * wB.x + v1.y * wB.y + v1.z * wB.z + v1.w * wB.w;
  }
#pragma unroll
  for (int c = 0; c < 5; ++c) {
    part[c] += __shfl_xor(part[c], 1);
    part[c] += __shfl_xor(part[c], 2);
    part[c] += __shfl_xor(part[c], 4);
  }
  if (fh == 0) {
#pragma unroll
    for (int c = 0; c < 5; ++c)
      ht2b[(size_t)d * OUT_DIM + jb + c] = f2bf(part[c] * dd);
  }
}

// ---------------- agg2 + bias2 + log-softmax (XCD-aligned mapping) ----------
__global__ __launch_bounds__(256) void k_agg2(const int* __restrict__ cnt,
                                              const unsigned short* __restrict__ elist2,
                                              const unsigned short* __restrict__ ht2b,
                                              const float* __restrict__ b2,
                                              float* __restrict__ out) {
  const int wave = threadIdx.x >> 6;
  const int lane = threadIdx.x & 63;
  const int dl = (blockIdx.x >> 3) * 4 + wave;
  if (dl >= NODES_PER_GRP) return;
  const int d = (blockIdx.x & 7) * NODES_PER_GRP + dl;
  const int g = lane >> 3;            // edge group 0..7
  const int fh = lane & 7;            // quad 0..7 (+ fh<2 carry quads 8,9)
  const bool extra = fh < 2;

  int cn = cnt[d];
  if (cn > BCAP) cn = BCAP;
  const unsigned short* __restrict__ bucket = elist2 + d * BCAP;
  float4 a0 = {0.f, 0.f, 0.f, 0.f};
  float4 a1 = {0.f, 0.f, 0.f, 0.f};
#pragma unroll 2
  for (int j = g; j < cn; j += 8) {
    int s = bucket[j];
    const uint2* __restrict__ p = (const uint2*)(ht2b + (size_t)s * OUT_DIM);
    uint2 q0 = p[fh];
    a0.x += __uint_as_float(q0.x << 16);
    a0.y += __uint_as_float(q0.x & 0xFFFF0000u);
    a0.z += __uint_as_float(q0.y << 16);
    a0.w += __uint_as_float(q0.y & 0xFFFF0000u);
    if (extra) {
      uint2 q1 = p[8 + fh];
      a1.x += __uint_as_float(q1.x << 16);
      a1.y += __uint_as_float(q1.x & 0xFFFF0000u);
      a1.z += __uint_as_float(q1.y << 16);
      a1.w += __uint_as_float(q1.y & 0xFFFF0000u);
    }
  }
#pragma unroll
  for (int m = 32; m >= 8; m >>= 1) {
    a0.x += __shfl_xor(a0.x, m); a0.y += __shfl_xor(a0.y, m);
    a0.z += __shfl_xor(a0.z, m); a0.w += __shfl_xor(a0.w, m);
    a1.x += __shfl_xor(a1.x, m); a1.y += __shfl_xor(a1.y, m);
    a1.z += __shfl_xor(a1.z, m); a1.w += __shfl_xor(a1.w, m);
  }

  // self-loop (ht2b already dis[s]-scaled)
  {
    const uint2* __restrict__ ps = (const uint2*)(ht2b + (size_t)d * OUT_DIM);
    uint2 s0 = ps[fh];
    a0.x += __uint_as_float(s0.x << 16);
    a0.y += __uint_as_float(s0.x & 0xFFFF0000u);
    a0.z += __uint_as_float(s0.y << 16);
    a0.w += __uint_as_float(s0.y & 0xFFFF0000u);
    if (extra) {
      uint2 s1 = ps[8 + fh];
      a1.x += __uint_as_float(s1.x << 16);
      a1.y += __uint_as_float(s1.x & 0xFFFF0000u);
      a1.z += __uint_as_float(s1.y << 16);
      a1.w += __uint_as_float(s1.y & 0xFFFF0000u);
    }
  }

  float dd = rsqrtf((float)cn + 1.0f);
  float4 bb0 = *(const float4*)(b2 + fh * 4);
  float4 v0, v1;
  v0.x = a0.x * dd + bb0.x;
  v0.y = a0.y * dd + bb0.y;
  v0.z = a0.z * dd + bb0.z;
  v0.w = a0.w * dd + bb0.w;
  float mm = fmaxf(fmaxf(v0.x, v0.y), fmaxf(v0.z, v0.w));
  if (extra) {
    float4 bb1 = *(const float4*)(b2 + 32 + fh * 4);
    v1.x = a1.x * dd + bb1.x;
    v1.y = a1.y * dd + bb1.y;
    v1.z = a1.z * dd + bb1.z;
    v1.w = a1.w * dd + bb1.w;
    mm = fmaxf(mm, fmaxf(fmaxf(v1.x, v1.y), fmaxf(v1.z, v1.w)));
  }
  mm = fmaxf(mm, __shfl_xor(mm, 1));
  mm = fmaxf(mm, __shfl_xor(mm, 2));
  mm = fmaxf(mm, __shfl_xor(mm, 4));
  float e = expf(v0.x - mm) + expf(v0.y - mm) + expf(v0.z - mm) + expf(v0.w - mm);
  if (extra)
    e += expf(v1.x - mm) + expf(v1.y - mm) + expf(v1.z - mm) + expf(v1.w - mm);
  e += __shfl_xor(e, 1);
  e += __shfl_xor(e, 2);
  e += __shfl_xor(e, 4);
  float ls = logf(e) + mm;

  if (g == 0) {
    float4 r;
    r.x = v0.x - ls; r.y = v0.y - ls; r.z = v0.z - ls; r.w = v0.w - ls;
    *(float4*)(out + (size_t)d * OUT_DIM + fh * 4) = r;
    if (extra) {
      float4 r1;
      r1.x = v1.x - ls; r1.y = v1.y - ls; r1.z = v1.z - ls; r1.w = v1.w - ls;
      *(float4*)(out + (size_t)d * OUT_DIM + 32 + fh * 4) = r1;
    }
  }
}

// ---------------- launch ----------------
extern "C" void kernel_launch(void* const* d_in, const int* in_sizes, int n_in,
                              void* d_out, int out_size, void* d_ws, size_t ws_size,
                              hipStream_t stream) {
  const float* x  = (const float*)d_in[0];
  const int*   ei = (const int*)  d_in[1];
  const float* W1 = (const float*)d_in[2];
  const float* b1 = (const float*)d_in[3];
  const float* W2 = (const float*)d_in[4];
  const float* b2 = (const float*)d_in[5];
  float* out = (float*)d_out;
  float* ws  = (float*)d_ws;

  // ws layout (float offsets)
  unsigned short* ht1b = (unsigned short*)ws;              // 3.2M ushorts
  unsigned short* ht2b = (unsigned short*)(ws + 1600000);  // 2.0M ushorts
  unsigned short* Wb1 = (unsigned short*)(ws + 2600000);   // 32,768 ushorts
  float* w2t  = ws + 2620000;                              // 2,560
  int* cnt    = (int*)(ws + 2630000);                      // 50,000 ints
  unsigned short* elist2 = (unsigned short*)(ws + 2681200); // 4.8M ushorts

  k_init<<<196, 256, 0, stream>>>(W1, W2, Wb1, w2t, cnt);
  k_fill<<<FILL_BLOCKS, 512, 0, stream>>>(ei, cnt, elist2);
  k_gemm1<<<GEMM1_BLOCKS, 512, 0, stream>>>(x, Wb1, ht1b);
  k_agg1g2<<<AGG_BLOCKS, 256, 0, stream>>>(cnt, elist2, ht1b, b1, w2t, ht2b);
  k_agg2<<<AGG_BLOCKS, 256, 0, stream>>>(cnt, elist2, ht2b, b2, out);
}

// Round 22
// 125.430 us; speedup vs baseline: 1.1175x; 1.1175x over previous
//
#include <hip/hip_runtime.h>
#include <math.h>
#include <float.h>

#define N_NODES 50000
#define N_EDGES 800000
#define IN_DIM  512
#define HID_DIM 64
#define OUT_DIM 40
#define GEMM1_BLOCKS 782
#define FILL_BLOCKS 1568        // 8 groups x 196 blocks
#define NODES_PER_GRP 6250      // 50000 / 8
#define BCAP 96                 // bucket capacity (deg ~ Poisson(16))
#define AGG_Q 1563              // ceil(6250/4)
#define AGG_BLOCKS (8 * AGG_Q)  // 12504
#define GF_BLOCKS 2350          // 3*782 interleaved + 4 tail fill

typedef __attribute__((ext_vector_type(8))) short bf16x8;
typedef __attribute__((ext_vector_type(4))) float f32x4;

#define GLOAD_LDS(SRC, DST)                                                   \
  __builtin_amdgcn_global_load_lds(                                           \
      (const __attribute__((address_space(1))) void*)(SRC),                   \
      (__attribute__((address_space(3))) void*)(DST), 16, 0, 0)

// ---------------- Threefry-2x32, JAX-exact, key = (0, 42) ----------------
__device__ __forceinline__ unsigned rotl32(unsigned v, int n) {
  return (v << n) | (v >> (32 - n));
}

__device__ __forceinline__ void threefry2x32_0_42(unsigned x0, unsigned x1,
                                                  unsigned &o0, unsigned &o1) {
  const unsigned ks0 = 0u;
  const unsigned ks1 = 42u;
  const unsigned ks2 = 0u ^ 42u ^ 0x1BD11BDAu;
  x0 += ks0; x1 += ks1;
  x0 += x1; x1 = rotl32(x1, 13); x1 ^= x0;
  x0 += x1; x1 = rotl32(x1, 15); x1 ^= x0;
  x0 += x1; x1 = rotl32(x1, 26); x1 ^= x0;
  x0 += x1; x1 = rotl32(x1,  6); x1 ^= x0;
  x0 += ks1; x1 += ks2 + 1u;
  x0 += x1; x1 = rotl32(x1, 17); x1 ^= x0;
  x0 += x1; x1 = rotl32(x1, 29); x1 ^= x0;
  x0 += x1; x1 = rotl32(x1, 16); x1 ^= x0;
  x0 += x1; x1 = rotl32(x1, 24); x1 ^= x0;
  x0 += ks2; x1 += ks0 + 2u;
  x0 += x1; x1 = rotl32(x1, 13); x1 ^= x0;
  x0 += x1; x1 = rotl32(x1, 15); x1 ^= x0;
  x0 += x1; x1 = rotl32(x1, 26); x1 ^= x0;
  x0 += x1; x1 = rotl32(x1,  6); x1 ^= x0;
  x0 += ks0; x1 += ks1 + 3u;
  x0 += x1; x1 = rotl32(x1, 17); x1 ^= x0;
  x0 += x1; x1 = rotl32(x1, 29); x1 ^= x0;
  x0 += x1; x1 = rotl32(x1, 16); x1 ^= x0;
  x0 += x1; x1 = rotl32(x1, 24); x1 ^= x0;
  x0 += ks1; x1 += ks2 + 4u;
  x0 += x1; x1 = rotl32(x1, 13); x1 ^= x0;
  x0 += x1; x1 = rotl32(x1, 15); x1 ^= x0;
  x0 += x1; x1 = rotl32(x1, 26); x1 ^= x0;
  x0 += x1; x1 = rotl32(x1,  6); x1 ^= x0;
  x0 += ks2; x1 += ks0 + 5u;
  o0 = x0; o1 = x1;
}

__device__ __forceinline__ unsigned short f2bf(float f) {
  unsigned u = __float_as_uint(f);
  unsigned r = u + 0x7FFFu + ((u >> 16) & 1u);   // RNE
  return (unsigned short)(r >> 16);
}

// ---------------- init: zero cnt + weight repack (fused, no deps) -----------
__global__ void k_init(const float* __restrict__ W1, const float* __restrict__ W2,
                       unsigned short* __restrict__ Wb1, float* __restrict__ w2t,
                       int* __restrict__ cnt) {
  int i = blockIdx.x * 256 + threadIdx.x;
  if (i < N_NODES) cnt[i] = 0;
  if (i < IN_DIM * HID_DIM) {
    int j = i & 7;
    int lane = (i >> 3) & 63;
    int cg = (i >> 9) & 3;
    int kb = i >> 11;
    int k = kb * 32 + ((lane >> 4) << 3) + j;
    int c = cg * 16 + (lane & 15);
    Wb1[i] = f2bf(W1[k * HID_DIM + c]);
  }
  if (i < HID_DIM * OUT_DIM) {
    int j = i >> 6;           // output col 0..39
    int k = i & 63;           // hidden idx
    w2t[i] = W2[k * OUT_DIM + j];
  }
}

// ---- gemm1 + bucket fill, ROLE-INTERLEAVED (1:2 mix resident from t=0) -----
// b%3==0 -> gemm1 row-block q=b/3 (async global_load_lds f32, swizzled).
// else   -> fill block fb=2q+r-1 (+ tail fb=1564..1567 for b>=2346).
__global__ __launch_bounds__(512) void k_gemm1_fill(
    const int* __restrict__ ei, int* __restrict__ cnt,
    unsigned short* __restrict__ elist2,
    const float* __restrict__ x, const unsigned short* __restrict__ Wb1,
    unsigned short* __restrict__ ht1b) {
  __shared__ unsigned char sxa[2][16384];   // 64 rows x 64 f32 per chunk

  const int b = blockIdx.x;
  const int q = b / 3;
  const int r = b - 3 * q;
  const bool is_gemm = (r == 0) && (q < GEMM1_BLOCKS);

  if (!is_gemm) {
    int fb = (b < 3 * GEMM1_BLOCKS) ? (2 * q + r - 1) : (1564 + (b - 2346));
    if (fb >= FILL_BLOCKS) return;
    const int grp = fb & 7;
    const int ord = fb >> 3;                     // 0..195 within group
    const int lo = grp * NODES_PER_GRP;
    const int hi = lo + NODES_PER_GRP;
    const int ebase = ord * 512 + threadIdx.x;
    int dv[8];
#pragma unroll
    for (int i = 0; i < 8; ++i) {
      int e = ebase + i * (196 * 512);
      dv[i] = (e < N_EDGES) ? ei[N_EDGES + e] : -1;
    }
#pragma unroll
    for (int i = 0; i < 8; ++i) {
      if (dv[i] >= lo && dv[i] < hi) {
        int s = ei[ebase + i * (196 * 512)];
        int slot = atomicAdd(&cnt[dv[i]], 1);
        if (slot < BCAP) elist2[dv[i] * BCAP + slot] = (unsigned short)s;
      }
    }
    return;
  }

  const int tid = threadIdx.x;
  const int lane = tid & 63;
  const int wave = tid >> 6;          // 0..7
  const int brow = q * 64;

  f32x4 acc[2];
  acc[0] = (f32x4){0.f, 0.f, 0.f, 0.f};
  acc[1] = (f32x4){0.f, 0.f, 0.f, 0.f};

  const bf16x8* __restrict__ Wv = (const bf16x8*)Wb1;

  int srow[2], soff[2];
#pragma unroll
  for (int i = 0; i < 2; ++i) {
    int p = wave * 2048 + i * 1024 + lane * 16;
    int row = p >> 8;
    int bb = p & 255;
    int gr2 = brow + row;
    if (gr2 >= N_NODES) gr2 = N_NODES - 1;
    srow[i] = gr2;
    soff[i] = bb ^ ((row & 7) << 4);   // byte offset within the 256B k-slice
  }

#define ISSUE(B, KC)                                                          \
  {                                                                           \
    _Pragma("unroll")                                                         \
    for (int i = 0; i < 2; ++i) {                                             \
      const char* src = (const char*)(x + (size_t)srow[i] * IN_DIM +          \
                                      (KC) * 64) + soff[i];                   \
      GLOAD_LDS(src, &sxa[B][wave * 2048 + i * 1024]);                        \
    }                                                                         \
  }

  ISSUE(0, 0)
  __syncthreads();

  const int arow = 16 * (wave & 3) + (lane & 15);   // logical row
  const int rsw = (arow & 7) << 4;
  const int kbyte = (lane >> 4) << 5;               // (lane>>4)*8 f32 = 32B
  const int cgb = 2 * (wave >> 2);                  // col-group base

  int buf = 0;
  for (int kc = 0; kc < 8; ++kc) {
    if (kc < 7) ISSUE(buf ^ 1, kc + 1)    // async DMA overlaps compute
#pragma unroll
    for (int ks = 0; ks < 2; ++ks) {
      int lin = arow * 256 + ks * 128 + kbyte;
      float4 fa = *(const float4*)(&sxa[buf][lin ^ rsw]);
      float4 fb4 = *(const float4*)(&sxa[buf][(lin + 16) ^ rsw]);
      union { unsigned short u[8]; bf16x8 v; } pk;
      pk.u[0] = f2bf(fa.x); pk.u[1] = f2bf(fa.y);
      pk.u[2] = f2bf(fa.z); pk.u[3] = f2bf(fa.w);
      pk.u[4] = f2bf(fb4.x); pk.u[5] = f2bf(fb4.y);
      pk.u[6] = f2bf(fb4.z); pk.u[7] = f2bf(fb4.w);
      int kb = kc * 2 + ks;
#pragma unroll
      for (int c = 0; c < 2; ++c) {
        bf16x8 bw = Wv[(kb * 4 + cgb + c) * 64 + lane];
        acc[c] = __builtin_amdgcn_mfma_f32_16x16x32_bf16(pk.v, bw, acc[c], 0, 0, 0);
      }
    }
    __syncthreads();                      // drains vmcnt -> next buf ready
    buf ^= 1;
  }
#undef ISSUE

#pragma unroll
  for (int p = 0; p < 4; ++p) {
    int grow = brow + 16 * (wave & 3) + ((lane >> 4) << 2) + p;
    if (grow < N_NODES) {
#pragma unroll
      for (int c = 0; c < 2; ++c) {
        ht1b[(size_t)grow * HID_DIM + (cgb + c) * 16 + (lane & 15)] =
            f2bf(acc[c][p]);
      }
    }
  }
}

// ---- agg1 + gemm2 fused (ushort buckets, XCD-aligned node mapping) ---------
__global__ __launch_bounds__(256) void k_agg1g2(const int* __restrict__ cnt,
                                                const unsigned short* __restrict__ elist2,
                                                const unsigned short* __restrict__ ht1b,
                                                const float* __restrict__ b1,
                                                const float* __restrict__ w2t,
                                                unsigned short* __restrict__ ht2b) {
  const int wave = threadIdx.x >> 6;
  const int lane = threadIdx.x & 63;
  const int dl = (blockIdx.x >> 3) * 4 + wave;
  if (dl >= NODES_PER_GRP) return;
  const int d = (blockIdx.x & 7) * NODES_PER_GRP + dl;
  const int g = lane >> 3;        // edge group 0..7
  const int fh = lane & 7;        // feature quad pair: quads fh and fh+8

  unsigned t0, t1;
  threefry2x32_0_42(0u, (unsigned)d * 64u + (unsigned)lane, t0, t1);
  unsigned long long keep = __ballot(!((t0 ^ t1) & 0x80000000u));

  int cn = cnt[d];
  if (cn > BCAP) cn = BCAP;
  const unsigned short* __restrict__ bucket = elist2 + d * BCAP;
  float4 a0 = {0.f, 0.f, 0.f, 0.f};
  float4 a1 = {0.f, 0.f, 0.f, 0.f};
#pragma unroll 2
  for (int j = g; j < cn; j += 8) {
    int s = bucket[j];
    float ds = rsqrtf((float)cnt[s] + 1.0f);
    const uint2* __restrict__ p = (const uint2*)(ht1b + (size_t)s * HID_DIM);
    uint2 q0 = p[fh];
    uint2 q1 = p[fh + 8];
    a0.x += __uint_as_float(q0.x << 16) * ds;
    a0.y += __uint_as_float(q0.x & 0xFFFF0000u) * ds;
    a0.z += __uint_as_float(q0.y << 16) * ds;
    a0.w += __uint_as_float(q0.y & 0xFFFF0000u) * ds;
    a1.x += __uint_as_float(q1.x << 16) * ds;
    a1.y += __uint_as_float(q1.x & 0xFFFF0000u) * ds;
    a1.z += __uint_as_float(q1.y << 16) * ds;
    a1.w += __uint_as_float(q1.y & 0xFFFF0000u) * ds;
  }
#pragma unroll
  for (int m = 32; m >= 8; m >>= 1) {
    a0.x += __shfl_xor(a0.x, m); a0.y += __shfl_xor(a0.y, m);
    a0.z += __shfl_xor(a0.z, m); a0.w += __shfl_xor(a0.w, m);
    a1.x += __shfl_xor(a1.x, m); a1.y += __shfl_xor(a1.y, m);
    a1.z += __shfl_xor(a1.z, m); a1.w += __shfl_xor(a1.w, m);
  }

  // self-loop (s = d), then bias + relu + dropout on ALL lanes
  float dd = rsqrtf((float)cn + 1.0f);
  {
    const uint2* __restrict__ ps = (const uint2*)(ht1b + (size_t)d * HID_DIM);
    uint2 s0 = ps[fh];
    uint2 s1 = ps[fh + 8];
    a0.x += __uint_as_float(s0.x << 16) * dd;
    a0.y += __uint_as_float(s0.x & 0xFFFF0000u) * dd;
    a0.z += __uint_as_float(s0.y << 16) * dd;
    a0.w += __uint_as_float(s0.y & 0xFFFF0000u) * dd;
    a1.x += __uint_as_float(s1.x << 16) * dd;
    a1.y += __uint_as_float(s1.x & 0xFFFF0000u) * dd;
    a1.z += __uint_as_float(s1.y << 16) * dd;
    a1.w += __uint_as_float(s1.y & 0xFFFF0000u) * dd;
  }
  float4 bb0 = *(const float4*)(b1 + fh * 4);
  float4 bb1 = *(const float4*)(b1 + fh * 4 + 32);
  int f0 = fh * 4;
  float4 v0, v1;
  v0.x = fmaxf(a0.x * dd + bb0.x, 0.f) * (((keep >> (f0 + 0)) & 1) ? 2.f : 0.f);
  v0.y = fmaxf(a0.y * dd + bb0.y, 0.f) * (((keep >> (f0 + 1)) & 1) ? 2.f : 0.f);
  v0.z = fmaxf(a0.z * dd + bb0.z, 0.f) * (((keep >> (f0 + 2)) & 1) ? 2.f : 0.f);
  v0.w = fmaxf(a0.w * dd + bb0.w, 0.f) * (((keep >> (f0 + 3)) & 1) ? 2.f : 0.f);
  v1.x = fmaxf(a1.x * dd + bb1.x, 0.f) * (((keep >> (f0 + 32)) & 1) ? 2.f : 0.f);
  v1.y = fmaxf(a1.y * dd + bb1.y, 0.f) * (((keep >> (f0 + 33)) & 1) ? 2.f : 0.f);
  v1.z = fmaxf(a1.z * dd + bb1.z, 0.f) * (((keep >> (f0 + 34)) & 1) ? 2.f : 0.f);
  v1.w = fmaxf(a1.w * dd + bb1.w, 0.f) * (((keep >> (f0 + 35)) & 1) ? 2.f : 0.f);

  // mini-GEMM: lane (g,fh) partials for cols j=g*5+c over its 8 k's;
  // reduce across fh via xor 1,2,4.
  const int jb = g * 5;
  float part[5];
#pragma unroll
  for (int c = 0; c < 5; ++c) {
    const float* __restrict__ wr = w2t + (jb + c) * 64;
    float4 wA = *(const float4*)(wr + f0);
    float4 wB = *(const float4*)(wr + 32 + f0);
    part[c] = v0.x * wA.x + v0.y * wA.y + v0.z * wA.z + v0.w * wA.w +
              v1.x * wB.x + v1.y * wB.y + v1.z * wB.z + v1.w * wB.w;
  }
#pragma unroll
  for (int c = 0; c < 5; ++c) {
    part[c] += __shfl_xor(part[c], 1);
    part[c] += __shfl_xor(part[c], 2);
    part[c] += __shfl_xor(part[c], 4);
  }
  if (fh == 0) {
#pragma unroll
    for (int c = 0; c < 5; ++c)
      ht2b[(size_t)d * OUT_DIM + jb + c] = f2bf(part[c] * dd);
  }
}

// ---------------- agg2 + bias2 + log-softmax (XCD-aligned mapping) ----------
__global__ __launch_bounds__(256) void k_agg2(const int* __restrict__ cnt,
                                              const unsigned short* __restrict__ elist2,
                                              const unsigned short* __restrict__ ht2b,
                                              const float* __restrict__ b2,
                                              float* __restrict__ out) {
  const int wave = threadIdx.x >> 6;
  const int lane = threadIdx.x & 63;
  const int dl = (blockIdx.x >> 3) * 4 + wave;
  if (dl >= NODES_PER_GRP) return;
  const int d = (blockIdx.x & 7) * NODES_PER_GRP + dl;
  const int g = lane >> 3;            // edge group 0..7
  const int fh = lane & 7;            // quad 0..7 (+ fh<2 carry quads 8,9)
  const bool extra = fh < 2;

  int cn = cnt[d];
  if (cn > BCAP) cn = BCAP;
  const unsigned short* __restrict__ bucket = elist2 + d * BCAP;
  float4 a0 = {0.f, 0.f, 0.f, 0.f};
  float4 a1 = {0.f, 0.f, 0.f, 0.f};
#pragma unroll 2
  for (int j = g; j < cn; j += 8) {
    int s = bucket[j];
    const uint2* __restrict__ p = (const uint2*)(ht2b + (size_t)s * OUT_DIM);
    uint2 q0 = p[fh];
    a0.x += __uint_as_float(q0.x << 16);
    a0.y += __uint_as_float(q0.x & 0xFFFF0000u);
    a0.z += __uint_as_float(q0.y << 16);
    a0.w += __uint_as_float(q0.y & 0xFFFF0000u);
    if (extra) {
      uint2 q1 = p[8 + fh];
      a1.x += __uint_as_float(q1.x << 16);
      a1.y += __uint_as_float(q1.x & 0xFFFF0000u);
      a1.z += __uint_as_float(q1.y << 16);
      a1.w += __uint_as_float(q1.y & 0xFFFF0000u);
    }
  }
#pragma unroll
  for (int m = 32; m >= 8; m >>= 1) {
    a0.x += __shfl_xor(a0.x, m); a0.y += __shfl_xor(a0.y, m);
    a0.z += __shfl_xor(a0.z, m); a0.w += __shfl_xor(a0.w, m);
    a1.x += __shfl_xor(a1.x, m); a1.y += __shfl_xor(a1.y, m);
    a1.z += __shfl_xor(a1.z, m); a1.w += __shfl_xor(a1.w, m);
  }

  // self-loop (ht2b already dis[s]-scaled)
  {
    const uint2* __restrict__ ps = (const uint2*)(ht2b + (size_t)d * OUT_DIM);
    uint2 s0 = ps[fh];
    a0.x += __uint_as_float(s0.x << 16);
    a0.y += __uint_as_float(s0.x & 0xFFFF0000u);
    a0.z += __uint_as_float(s0.y << 16);
    a0.w += __uint_as_float(s0.y & 0xFFFF0000u);
    if (extra) {
      uint2 s1 = ps[8 + fh];
      a1.x += __uint_as_float(s1.x << 16);
      a1.y += __uint_as_float(s1.x & 0xFFFF0000u);
      a1.z += __uint_as_float(s1.y << 16);
      a1.w += __uint_as_float(s1.y & 0xFFFF0000u);
    }
  }

  float dd = rsqrtf((float)cn + 1.0f);
  float4 bb0 = *(const float4*)(b2 + fh * 4);
  float4 v0, v1;
  v0.x = a0.x * dd + bb0.x;
  v0.y = a0.y * dd + bb0.y;
  v0.z = a0.z * dd + bb0.z;
  v0.w = a0.w * dd + bb0.w;
  float mm = fmaxf(fmaxf(v0.x, v0.y), fmaxf(v0.z, v0.w));
  if (extra) {
    float4 bb1 = *(const float4*)(b2 + 32 + fh * 4);
    v1.x = a1.x * dd + bb1.x;
    v1.y = a1.y * dd + bb1.y;
    v1.z = a1.z * dd + bb1.z;
    v1.w = a1.w * dd + bb1.w;
    mm = fmaxf(mm, fmaxf(fmaxf(v1.x, v1.y), fmaxf(v1.z, v1.w)));
  }
  mm = fmaxf(mm, __shfl_xor(mm, 1));
  mm = fmaxf(mm, __shfl_xor(mm, 2));
  mm = fmaxf(mm, __shfl_xor(mm, 4));
  float e = expf(v0.x - mm) + expf(v0.y - mm) + expf(v0.z - mm) + expf(v0.w - mm);
  if (extra)
    e += expf(v1.x - mm) + expf(v1.y - mm) + expf(v1.z - mm) + expf(v1.w - mm);
  e += __shfl_xor(e, 1);
  e += __shfl_xor(e, 2);
  e += __shfl_xor(e, 4);
  float ls = logf(e) + mm;

  if (g == 0) {
    float4 r;
    r.x = v0.x - ls; r.y = v0.y - ls; r.z = v0.z - ls; r.w = v0.w - ls;
    *(float4*)(out + (size_t)d * OUT_DIM + fh * 4) = r;
    if (extra) {
      float4 r1;
      r1.x = v1.x - ls; r1.y = v1.y - ls; r1.z = v1.z - ls; r1.w = v1.w - ls;
      *(float4*)(out + (size_t)d * OUT_DIM + 32 + fh * 4) = r1;
    }
  }
}

// ---------------- launch ----------------
extern "C" void kernel_launch(void* const* d_in, const int* in_sizes, int n_in,
                              void* d_out, int out_size, void* d_ws, size_t ws_size,
                              hipStream_t stream) {
  const float* x  = (const float*)d_in[0];
  const int*   ei = (const int*)  d_in[1];
  const float* W1 = (const float*)d_in[2];
  const float* b1 = (const float*)d_in[3];
  const float* W2 = (const float*)d_in[4];
  const float* b2 = (const float*)d_in[5];
  float* out = (float*)d_out;
  float* ws  = (float*)d_ws;

  // ws layout (float offsets)
  unsigned short* ht1b = (unsigned short*)ws;              // 3.2M ushorts
  unsigned short* ht2b = (unsigned short*)(ws + 1600000);  // 2.0M ushorts
  unsigned short* Wb1 = (unsigned short*)(ws + 2600000);   // 32,768 ushorts
  float* w2t  = ws + 2620000;                              // 2,560
  int* cnt    = (int*)(ws + 2630000);                      // 50,000 ints
  unsigned short* elist2 = (unsigned short*)(ws + 2681200); // 4.8M ushorts

  k_init<<<196, 256, 0, stream>>>(W1, W2, Wb1, w2t, cnt);
  k_gemm1_fill<<<GF_BLOCKS, 512, 0, stream>>>(ei, cnt, elist2, x, Wb1, ht1b);
  k_agg1g2<<<AGG_BLOCKS, 256, 0, stream>>>(cnt, elist2, ht1b, b1, w2t, ht2b);
  k_agg2<<<AGG_BLOCKS, 256, 0, stream>>>(cnt, elist2, ht2b, b2, out);
}